// Round 1
// baseline (136.699 us; speedup 1.0000x reference)
//
#include <hip/hip_runtime.h>
#include <math.h>

#define VOCAB  50000
#define D_EMB  300
#define NBINS  11
#define BATCH  64
#define LQ     32
#define LD     1024
#define DTILE  64
#define NDT    (LD / DTILE)   // 16
#define NSTEP  10             // K padded to 320 = 10 * 32 (MFMA K=32 steps)
#define KPAD   320

// ---- workspace layout ----
// [0, 1.44MB)      partial  [dt][b][q][k] f32  (transposed: block writes contiguous)
// [1.44MB, +32MB)  bf16 table [VOCAB][KPAD]    (row-major, 640 B rows)
// [+, +200KB)      inv-norm per vocab row (from ROUNDED values)
#define PARTIAL_BYTES ((size_t)NDT * BATCH * LQ * NBINS * 4)   // 1,441,792
#define TB_OFF        PARTIAL_BYTES
#define TB_BYTES      ((size_t)VOCAB * KPAD * 2)               // 32,000,000
#define INV_OFF       (TB_OFF + TB_BYTES)
#define INV_BYTES     ((size_t)VOCAB * 4)
#define WS_NEED       (INV_OFF + INV_BYTES)                    // 33,641,792

typedef __attribute__((ext_vector_type(8))) short short8;          // 8 bf16
typedef __attribute__((ext_vector_type(4))) float floatx4;         // MFMA C/D
typedef __attribute__((ext_vector_type(4))) unsigned short us4;    // 4 bf16
typedef unsigned int u32;

__constant__ float c_mu[NBINS]  = {1.0f, 0.9f, 0.7f, 0.5f, 0.3f, 0.1f,
                                   -0.1f, -0.3f, -0.5f, -0.7f, -0.9f};
// 1 / (2*sigma^2): sigma=1e-3 -> 5e5 ; sigma=0.1 -> 50
__constant__ float c_is2[NBINS] = {500000.0f, 50.f, 50.f, 50.f, 50.f, 50.f,
                                   50.f, 50.f, 50.f, 50.f, 50.f};

static __device__ __forceinline__ unsigned short f32_bf16(float f) {
  unsigned u = __float_as_uint(f);
  u += 0x7FFFu + ((u >> 16) & 1u);          // RNE
  return (unsigned short)(u >> 16);
}
static __device__ __forceinline__ float bf16_f32(unsigned short h) {
  return __uint_as_float(((unsigned)h) << 16);
}

// async global->LDS: 64 lanes x 16 B, LDS dest = uniform base + lane*16
static __device__ __forceinline__ void gload_lds16(const void* g, void* l) {
  __builtin_amdgcn_global_load_lds(
      (__attribute__((address_space(1))) u32*)g,
      (__attribute__((address_space(3))) u32*)l, 16, 0, 0);
}

// ---------------------------------------------------------------------------
// Prepass: word_emb (f32) -> bf16 table (rows padded to 320) + per-row
// inv-norm computed from the ROUNDED bf16 values (bin-0 exactness).
// One wave per vocab row; fully coalesced streaming.
__global__ __launch_bounds__(256) void knrm_prep(
    const float* __restrict__ word_emb,
    unsigned short* __restrict__ tb, float* __restrict__ invn)
{
  const int wid  = threadIdx.x >> 6;
  const int lane = threadIdx.x & 63;
  const int row  = blockIdx.x * 4 + wid;
  if (row >= VOCAB) return;
  const float4* src = (const float4*)(word_emb + (size_t)row * D_EMB);  // 75 f4
  const float4 a = src[lane];                        // elems 0..255
  float4 c = make_float4(0.f, 0.f, 0.f, 0.f);
  if (lane < 11) c = src[64 + lane];                 // elems 256..299, pad->319
  us4 ha, hc;
  ha.x = f32_bf16(a.x); ha.y = f32_bf16(a.y);
  ha.z = f32_bf16(a.z); ha.w = f32_bf16(a.w);
  hc.x = f32_bf16(c.x); hc.y = f32_bf16(c.y);
  hc.z = f32_bf16(c.z); hc.w = f32_bf16(c.w);
  float p = 0.f;
  { float x;
    x = bf16_f32(ha.x); p += x * x;  x = bf16_f32(ha.y); p += x * x;
    x = bf16_f32(ha.z); p += x * x;  x = bf16_f32(ha.w); p += x * x;
    x = bf16_f32(hc.x); p += x * x;  x = bf16_f32(hc.y); p += x * x;
    x = bf16_f32(hc.z); p += x * x;  x = bf16_f32(hc.w); p += x * x; }
#pragma unroll
  for (int off = 1; off < 64; off <<= 1) p += __shfl_xor(p, off);
  unsigned short* orow = tb + (size_t)row * KPAD;
  *(us4*)(orow + 4 * lane) = ha;
  if (lane < 16) *(us4*)(orow + 256 + 4 * lane) = hc;
  if (lane == 0) invn[row] = 1.f / fmaxf(sqrtf(p), 1e-12f);
}

// ---------------------------------------------------------------------------
// Main: one block = (batch b, 64-doc-token tile). Staging is pure async DMA
// in MFMA-fragment layout; norms are table lookups; epilogue unchanged.
__global__ __launch_bounds__(256) void knrm_main(
    const int* __restrict__ inputs_q, const int* __restrict__ inputs_d,
    const float* __restrict__ mask_d, const unsigned short* __restrict__ tb,
    const float* __restrict__ invn, float* __restrict__ partial)
{
  const int b    = blockIdx.y;
  const int dt   = blockIdx.x;
  const int tid  = threadIdx.x;
  const int wid  = tid >> 6;
  const int lane = tid & 63;
  const int khi  = lane >> 4;   // 0..3
  const int rl   = lane & 15;   // 0..15

  __shared__ __align__(16) short Afrag[2 * NSTEP * 512];  // 20 KB
  __shared__ __align__(16) short Bfrag[4 * NSTEP * 512];  // 40 KB
  __shared__ float invq_s[LQ], invd_s[DTILE], maskd_s[DTILE];
  __shared__ float red[4][16][NBINS];

  const int dbase = b * LD + dt * DTILE;

  // 60 (region, s) fragment blocks of 1 KB, 15 gload_lds per wave.
  // Lane l sources row tok(l&15), bytes khi*16 + 64*s of the bf16 row; the
  // HW writes them at LDS base + l*16 -> exactly the MFMA fragment layout.
  int tokX, tokY, ybase;
  short *dstX, *dstY;
  if (wid == 0)      { tokX = inputs_q[b * LQ + rl];        dstX = Afrag;
                       tokY = inputs_d[dbase + rl];         dstY = Bfrag;                  ybase = 0; }
  else if (wid == 1) { tokX = inputs_q[b * LQ + 16 + rl];   dstX = Afrag + NSTEP * 512;
                       tokY = inputs_d[dbase + rl];         dstY = Bfrag;                  ybase = 5; }
  else if (wid == 2) { tokX = inputs_d[dbase + 16 + rl];    dstX = Bfrag + NSTEP * 512;
                       tokY = inputs_d[dbase + 32 + rl];    dstY = Bfrag + 2 * NSTEP * 512; ybase = 0; }
  else               { tokX = inputs_d[dbase + 48 + rl];    dstX = Bfrag + 3 * NSTEP * 512;
                       tokY = inputs_d[dbase + 32 + rl];    dstY = Bfrag + 2 * NSTEP * 512; ybase = 5; }

  const char* srcX = (const char*)(tb + (size_t)tokX * KPAD) + khi * 16;
  const char* srcY = (const char*)(tb + (size_t)tokY * KPAD) + khi * 16;
#pragma unroll
  for (int s = 0; s < NSTEP; ++s)
    gload_lds16(srcX + 64 * s, dstX + s * 512);
#pragma unroll
  for (int s = 0; s < 5; ++s)
    gload_lds16(srcY + 64 * (ybase + s), dstY + (ybase + s) * 512);

  // precomputed inv-norms (overlaps with the async staging)
  if (tid < LQ)      invq_s[tid] = invn[inputs_q[b * LQ + tid]];
  else if (tid < 96) { const int d = tid - 32;
                       invd_s[d]  = invn[inputs_d[dbase + d]];
                       maskd_s[d] = mask_d[dbase + d]; }
  __syncthreads();   // drains vmcnt(0): all 60 KB landed

  // ---- MFMA: wave w computes C tiles (qt = w>>1) x (dt2 = 2*(w&1), +1)
  const int qt = wid >> 1, dp = wid & 1;
  const short* Ab = Afrag + qt * NSTEP * 512;
  const short* B0 = Bfrag + (2 * dp) * NSTEP * 512;
  const short* B1 = Bfrag + (2 * dp + 1) * NSTEP * 512;
  floatx4 acc0 = {0.f, 0.f, 0.f, 0.f};
  floatx4 acc1 = {0.f, 0.f, 0.f, 0.f};
#pragma unroll
  for (int s = 0; s < NSTEP; ++s) {
    const short8 a  = *(const short8*)(Ab + s * 512 + lane * 8);
    const short8 b0 = *(const short8*)(B0 + s * 512 + lane * 8);
    const short8 b1 = *(const short8*)(B1 + s * 512 + lane * 8);
    acc0 = __builtin_amdgcn_mfma_f32_16x16x32_bf16(a, b0, acc0, 0, 0, 0);
    acc1 = __builtin_amdgcn_mfma_f32_16x16x32_bf16(a, b1, acc1, 0, 0, 0);
  }

  // ---- epilogue: normalize, RBF bins, pool over this wave's 32 d-cols
  float ps[4][NBINS];
#pragma unroll
  for (int r = 0; r < 4; ++r)
#pragma unroll
    for (int k = 0; k < NBINS; ++k) ps[r][k] = 0.f;

  float iq[4];
#pragma unroll
  for (int r = 0; r < 4; ++r) iq[r] = invq_s[16 * qt + 4 * khi + r];

#pragma unroll
  for (int t = 0; t < 2; ++t) {
    const int   dl = 32 * dp + 16 * t + rl;   // C/D col = lane&15
    const float id = invd_s[dl];
    const float md = maskd_s[dl];
    const floatx4 acc = t ? acc1 : acc0;
#pragma unroll
    for (int r = 0; r < 4; ++r) {             // C/D row = 4*(lane>>4)+r
      const float sv = acc[r] * iq[r] * id;
#pragma unroll
      for (int k = 0; k < NBINS; ++k) {
        const float d = sv - c_mu[k];
        ps[r][k] += md * __expf(-d * d * c_is2[k]);
      }
    }
  }

#pragma unroll
  for (int off = 1; off < 16; off <<= 1)
#pragma unroll
    for (int r = 0; r < 4; ++r)
#pragma unroll
      for (int k = 0; k < NBINS; ++k)
        ps[r][k] += __shfl_xor(ps[r][k], off);

  if (rl == 0)
#pragma unroll
    for (int r = 0; r < 4; ++r)
#pragma unroll
      for (int k = 0; k < NBINS; ++k)
        red[wid][4 * khi + r][k] = ps[r][k];
  __syncthreads();

  // transposed partial [dt][b][q][k]: contiguous 1408 B per block, no RMW
  float* pout = partial + ((size_t)dt * BATCH + b) * (LQ * NBINS);
  for (int v = tid; v < LQ * NBINS; v += 256) {
    const int q = v / NBINS, k = v % NBINS;
    pout[v] = (q < 16) ? (red[0][q][k] + red[1][q][k])
                       : (red[2][q - 16][k] + red[3][q - 16][k]);
  }
}

// ---------------------------------------------------------------------------
// Fallback path (proven kernel, f32 gather + in-kernel conversion) for the
// case ws_size < WS_NEED. Only the partial write layout changed (transposed).
static __device__ __forceinline__ float stage_rows(
    const float* __restrict__ emb_row, short* __restrict__ region,
    int s_begin, int s_end, int khi, int lane)
{
  const float4* emb4 = (const float4*)emb_row;
  float p = 0.f;
  for (int s = s_begin; s < s_end; ++s) {
    const int k0 = 32 * s + 8 * khi;
    float4 fa = make_float4(0.f, 0.f, 0.f, 0.f);
    float4 fb = make_float4(0.f, 0.f, 0.f, 0.f);
    if (k0 < D_EMB)     fa = emb4[k0 >> 2];
    if (k0 + 4 < D_EMB) fb = emb4[(k0 >> 2) + 1];
    unsigned short h[8];
    h[0] = f32_bf16(fa.x); h[1] = f32_bf16(fa.y);
    h[2] = f32_bf16(fa.z); h[3] = f32_bf16(fa.w);
    h[4] = f32_bf16(fb.x); h[5] = f32_bf16(fb.y);
    h[6] = f32_bf16(fb.z); h[7] = f32_bf16(fb.w);
    short8 v;
#pragma unroll
    for (int j = 0; j < 8; ++j) {
      const float x = bf16_f32(h[j]);
      p += x * x;
      v[j] = (short)h[j];
    }
    *(short8*)(region + s * 512 + lane * 8) = v;
  }
  return p;
}

__global__ __launch_bounds__(256) void knrm_main_fb(
    const int* __restrict__ inputs_q, const int* __restrict__ inputs_d,
    const float* __restrict__ mask_d, const float* __restrict__ word_emb,
    float* __restrict__ partial)
{
  const int b    = blockIdx.y;
  const int dt   = blockIdx.x;
  const int tid  = threadIdx.x;
  const int wid  = tid >> 6;
  const int lane = tid & 63;
  const int khi  = lane >> 4;
  const int rl   = lane & 15;

  __shared__ __align__(16) short Afrag[2 * NSTEP * 512];
  __shared__ __align__(16) short Bfrag[4 * NSTEP * 512];
  __shared__ float sumsq_s[96];
  __shared__ float invq_s[LQ], invd_s[DTILE], maskd_s[DTILE];
  __shared__ float red[4][16][NBINS];

  if (tid < 96) sumsq_s[tid] = 0.f;
  if (tid < DTILE) maskd_s[tid] = mask_d[b * LD + dt * DTILE + tid];
  __syncthreads();

  {
    int tok; float p;
    if (wid == 0) {
      tok = inputs_q[b * LQ + rl];
      p = stage_rows(word_emb + (size_t)tok * D_EMB, Afrag, 0, NSTEP, khi, lane);
      p += __shfl_xor(p, 16); p += __shfl_xor(p, 32);
      if (lane < 16) atomicAdd(&sumsq_s[lane], p);
      tok = inputs_d[b * LD + dt * DTILE + rl];
      p = stage_rows(word_emb + (size_t)tok * D_EMB, Bfrag, 0, 5, khi, lane);
      p += __shfl_xor(p, 16); p += __shfl_xor(p, 32);
      if (lane < 16) atomicAdd(&sumsq_s[32 + lane], p);
    } else if (wid == 1) {
      tok = inputs_q[b * LQ + 16 + rl];
      p = stage_rows(word_emb + (size_t)tok * D_EMB, Afrag + NSTEP * 512, 0, NSTEP, khi, lane);
      p += __shfl_xor(p, 16); p += __shfl_xor(p, 32);
      if (lane < 16) atomicAdd(&sumsq_s[16 + lane], p);
      tok = inputs_d[b * LD + dt * DTILE + rl];
      p = stage_rows(word_emb + (size_t)tok * D_EMB, Bfrag, 5, NSTEP, khi, lane);
      p += __shfl_xor(p, 16); p += __shfl_xor(p, 32);
      if (lane < 16) atomicAdd(&sumsq_s[32 + lane], p);
    } else if (wid == 2) {
      tok = inputs_d[b * LD + dt * DTILE + 16 + rl];
      p = stage_rows(word_emb + (size_t)tok * D_EMB, Bfrag + NSTEP * 512, 0, NSTEP, khi, lane);
      p += __shfl_xor(p, 16); p += __shfl_xor(p, 32);
      if (lane < 16) atomicAdd(&sumsq_s[48 + lane], p);
      tok = inputs_d[b * LD + dt * DTILE + 32 + rl];
      p = stage_rows(word_emb + (size_t)tok * D_EMB, Bfrag + 2 * NSTEP * 512, 0, 5, khi, lane);
      p += __shfl_xor(p, 16); p += __shfl_xor(p, 32);
      if (lane < 16) atomicAdd(&sumsq_s[64 + lane], p);
    } else {
      tok = inputs_d[b * LD + dt * DTILE + 48 + rl];
      p = stage_rows(word_emb + (size_t)tok * D_EMB, Bfrag + 3 * NSTEP * 512, 0, NSTEP, khi, lane);
      p += __shfl_xor(p, 16); p += __shfl_xor(p, 32);
      if (lane < 16) atomicAdd(&sumsq_s[80 + lane], p);
      tok = inputs_d[b * LD + dt * DTILE + 32 + rl];
      p = stage_rows(word_emb + (size_t)tok * D_EMB, Bfrag + 2 * NSTEP * 512, 5, NSTEP, khi, lane);
      p += __shfl_xor(p, 16); p += __shfl_xor(p, 32);
      if (lane < 16) atomicAdd(&sumsq_s[64 + lane], p);
    }
  }
  __syncthreads();

  if (tid < 96) {
    const float s   = sumsq_s[tid];
    const float inv = 1.f / fmaxf(sqrtf(s), 1e-12f);
    if (tid < 32) invq_s[tid] = inv; else invd_s[tid - 32] = inv;
  }
  __syncthreads();

  const int qt = wid >> 1, dp = wid & 1;
  const short* Ab = Afrag + qt * NSTEP * 512;
  const short* B0 = Bfrag + (2 * dp) * NSTEP * 512;
  const short* B1 = Bfrag + (2 * dp + 1) * NSTEP * 512;
  floatx4 acc0 = {0.f, 0.f, 0.f, 0.f};
  floatx4 acc1 = {0.f, 0.f, 0.f, 0.f};
#pragma unroll
  for (int s = 0; s < NSTEP; ++s) {
    const short8 a  = *(const short8*)(Ab + s * 512 + lane * 8);
    const short8 b0 = *(const short8*)(B0 + s * 512 + lane * 8);
    const short8 b1 = *(const short8*)(B1 + s * 512 + lane * 8);
    acc0 = __builtin_amdgcn_mfma_f32_16x16x32_bf16(a, b0, acc0, 0, 0, 0);
    acc1 = __builtin_amdgcn_mfma_f32_16x16x32_bf16(a, b1, acc1, 0, 0, 0);
  }

  float ps[4][NBINS];
#pragma unroll
  for (int r = 0; r < 4; ++r)
#pragma unroll
    for (int k = 0; k < NBINS; ++k) ps[r][k] = 0.f;

  float iq[4];
#pragma unroll
  for (int r = 0; r < 4; ++r) iq[r] = invq_s[16 * qt + 4 * khi + r];

#pragma unroll
  for (int t = 0; t < 2; ++t) {
    const int   dl = 32 * dp + 16 * t + rl;
    const float id = invd_s[dl];
    const float md = maskd_s[dl];
    const floatx4 acc = t ? acc1 : acc0;
#pragma unroll
    for (int r = 0; r < 4; ++r) {
      const float sv = acc[r] * iq[r] * id;
#pragma unroll
      for (int k = 0; k < NBINS; ++k) {
        const float d = sv - c_mu[k];
        ps[r][k] += md * __expf(-d * d * c_is2[k]);
      }
    }
  }

#pragma unroll
  for (int off = 1; off < 16; off <<= 1)
#pragma unroll
    for (int r = 0; r < 4; ++r)
#pragma unroll
      for (int k = 0; k < NBINS; ++k)
        ps[r][k] += __shfl_xor(ps[r][k], off);

  if (rl == 0)
#pragma unroll
    for (int r = 0; r < 4; ++r)
#pragma unroll
      for (int k = 0; k < NBINS; ++k)
        red[wid][4 * khi + r][k] = ps[r][k];
  __syncthreads();

  float* pout = partial + ((size_t)dt * BATCH + b) * (LQ * NBINS);
  for (int v = tid; v < LQ * NBINS; v += 256) {
    const int q = v / NBINS, k = v % NBINS;
    pout[v] = (q < 16) ? (red[0][q][k] + red[1][q][k])
                       : (red[2][q - 16][k] + red[3][q - 16][k]);
  }
}

// ---------------------------------------------------------------------------
// Finalize: reduce d-tiles (coalesced across threads per tile), log, IDF
// attention weight, sum over q, dense+tanh.
__global__ __launch_bounds__(128) void knrm_finalize(
    const float* __restrict__ partial, const int* __restrict__ inputs_q,
    const float* __restrict__ mask_q, const float* __restrict__ attn_table,
    const float* __restrict__ idf_w, const float* __restrict__ idf_b,
    const float* __restrict__ dense_w, const float* __restrict__ dense_b,
    float* __restrict__ out)
{
  const int b   = blockIdx.x;
  const int tid = threadIdx.x;
  __shared__ float pool[LQ][NBINS];
  __shared__ float wq_s[LQ];
  __shared__ float lps[NBINS];

  for (int v = tid; v < LQ * NBINS; v += 128) {
    float s = 0.f;
#pragma unroll
    for (int t = 0; t < NDT; ++t)
      s += partial[((size_t)t * BATCH + b) * (LQ * NBINS) + v];
    pool[v / NBINS][v % NBINS] = logf(fmaxf(s, 1e-10f));
  }
  if (tid < LQ) {
    const int tok = inputs_q[b * LQ + tid];
    wq_s[tid] = mask_q[b * LQ + tid] * (attn_table[tok] * idf_w[0] + idf_b[0]);
  }
  __syncthreads();
  if (tid < NBINS) {
    float s = 0.f;
    for (int q = 0; q < LQ; ++q) s += pool[q][tid] * wq_s[q];
    lps[tid] = 0.01f * s;
  }
  __syncthreads();
  if (tid == 0) {
    float z = dense_b[0];
    for (int k = 0; k < NBINS; ++k) z += lps[k] * dense_w[k];
    out[b] = tanhf(z);
  }
}

extern "C" void kernel_launch(void* const* d_in, const int* in_sizes, int n_in,
                              void* d_out, int out_size, void* d_ws, size_t ws_size,
                              hipStream_t stream) {
  const int*   inputs_q  = (const int*)d_in[0];
  const int*   inputs_d  = (const int*)d_in[1];
  const float* mask_q    = (const float*)d_in[2];
  const float* mask_d    = (const float*)d_in[3];
  const float* word_emb  = (const float*)d_in[4];
  const float* attn_tab  = (const float*)d_in[5];
  const float* idf_w     = (const float*)d_in[6];
  const float* idf_b     = (const float*)d_in[7];
  const float* dense_w   = (const float*)d_in[8];
  const float* dense_b   = (const float*)d_in[9];
  float* out     = (float*)d_out;
  float* partial = (float*)d_ws;

  dim3 grid(NDT, BATCH);
  if (ws_size >= WS_NEED) {
    unsigned short* tb = (unsigned short*)((char*)d_ws + TB_OFF);
    float* invn        = (float*)((char*)d_ws + INV_OFF);
    knrm_prep<<<VOCAB / 4, 256, 0, stream>>>(word_emb, tb, invn);
    knrm_main<<<grid, 256, 0, stream>>>(inputs_q, inputs_d, mask_d, tb, invn, partial);
  } else {
    knrm_main_fb<<<grid, 256, 0, stream>>>(inputs_q, inputs_d, mask_d, word_emb, partial);
  }
  knrm_finalize<<<BATCH, 128, 0, stream>>>(partial, inputs_q, mask_q, attn_tab,
                                           idf_w, idf_b, dense_w, dense_b, out);
}